// Round 12
// baseline (226.065 us; speedup 1.0000x reference)
//
#include <hip/hip_runtime.h>

// LSTMDiscriminator: B=256, T=1024, I=200, H=16
// K0: prepack W_ih (permuted cols, bf16, fragment-linear) + fused bias -> ws
// K1: x_proj via MFMA 16x16x32 bf16; epilogue folds gate exp2 scale into bf16.
// K2: LSTM scan, ALL-GATES-IN-LANE variant: each lane computes all 4 gates of
//     its j (quad-redundant) -> zero mid-chain DPP, no vcc, 1 ds_read_b64/step.
// K3: head relu(h@W1^T+b1)@W2^T+b2 -> sigmoid -> mean over T ([b][j][t]).

#define T_LEN 1024
#define NB    256
#define CHUNK 128
#define NCH   (T_LEN / CHUNK)

#define F2I(x) __float_as_int(x)
#define I2F(x) __int_as_float(x)
// row_shl:4 (0x104): lane i reads lane i+4 -> brings h_{j+1} to lane of j
#define ROWSHL4(v) I2F(__builtin_amdgcn_update_dpp(F2I(v), F2I(v), 0x104, 0xF, 0xF, false))
#define RDLANE_I(v, l) __builtin_amdgcn_readlane((v), (l))

#define LOG2E 1.442695040888963f

typedef __bf16 bf16_t;
typedef bf16_t bf16x8 __attribute__((ext_vector_type(8)));
typedef float f32x4 __attribute__((ext_vector_type(4)));
typedef __fp16 half2_t __attribute__((ext_vector_type(2)));

#if __has_builtin(__builtin_amdgcn_exp2f)
__device__ __forceinline__ float fexp2(float x) { return __builtin_amdgcn_exp2f(x); }
#else
__device__ __forceinline__ float fexp2(float x) { return exp2f(x); }
#endif
#if __has_builtin(__builtin_amdgcn_rcpf)
__device__ __forceinline__ float frcp(float x) { return __builtin_amdgcn_rcpf(x); }
#else
__device__ __forceinline__ float frcp(float x) { return __fdividef(1.f, x); }
#endif

__device__ __forceinline__ half2_t i2h2(int x) { union { int i; half2_t h; } u; u.i = x; return u.h; }
__device__ __forceinline__ int h22i(half2_t h) { union { int i; half2_t h; } u; u.h = h; return u.i; }

#if __has_builtin(__builtin_amdgcn_fdot2)
#define FDOT2(a, b, c) __builtin_amdgcn_fdot2((a), (b), (c), false)
#else
__device__ __forceinline__ float FDOT2(half2_t a, half2_t b, float c) {
  return c + (float)a[0] * (float)b[0] + (float)a[1] * (float)b[1];
}
#endif

__device__ __forceinline__ float bf2f(unsigned short s) {
  return __uint_as_float(((unsigned int)s) << 16);
}
__device__ __forceinline__ unsigned int pkbf(float a, float b) {
  bf16_t x = (bf16_t)a, y = (bf16_t)b;
  unsigned short ux, uy;
  __builtin_memcpy(&ux, &x, 2); __builtin_memcpy(&uy, &y, 2);
  return (unsigned int)ux | ((unsigned int)uy << 16);
}

// ---------------- Kernel 0: prepack W (bf16, fragment-linear) + bias ----------------
__global__ __launch_bounds__(256) void k0_prep(
    const float* __restrict__ Wih, const float* __restrict__ bih,
    const float* __restrict__ bhh, bf16x8* __restrict__ wB,
    float* __restrict__ biasPerm)
{
  const int idx = blockIdx.x * 256 + threadIdx.x;   // 0..1791
  if (idx < 4 * 7 * 64) {
    const int f = idx / 448;
    const int rem = idx % 448;
    const int s = rem / 64;
    const int L = rem % 64;
    const int col = f * 16 + (L & 15);
    const int r = ((col & 3) << 4) | (col >> 2);
    const int k0 = s * 32 + (L >> 4) * 8;
    bf16x8 v;
#pragma unroll
    for (int e = 0; e < 8; ++e) {
      const int k = k0 + e;
      const float w = (k < 200) ? Wih[r * 200 + k] : 0.f;
      v[e] = (bf16_t)w;
    }
    wB[idx] = v;
  }
  if (blockIdx.x == 0 && threadIdx.x < 64) {
    const int c = threadIdx.x;
    const int r = ((c & 3) << 4) | (c >> 2);
    biasPerm[c] = bih[r] + bhh[r];
  }
}

// ---------------- Kernel 1: x projection via MFMA (R6-proven) ----------------
__global__ __launch_bounds__(256) void k1_xproj(
    const float* __restrict__ x, const bf16x8* __restrict__ wB,
    const float* __restrict__ biasPerm, unsigned short* __restrict__ xproj)
{
  __shared__ bf16x8 As[4 * 7 * 64];   // 28672 B
  __shared__ bf16x8 Bs[4 * 7 * 64];   // 28672 B

  const int tid = threadIdx.x;
  const int L = tid & 63;
  const int w = tid >> 6;
  const long row0 = (long)blockIdx.x * 64;

  if (w == 0) {
    const unsigned short* src = (const unsigned short*)wB;
    unsigned short* dst = (unsigned short*)Bs;
#pragma unroll
    for (int it = 0; it < 28; ++it) {
      __builtin_amdgcn_global_load_lds(
          (const __attribute__((address_space(1))) unsigned int*)(src + it * 512 + L * 8),
          (__attribute__((address_space(3))) unsigned int*)(dst + it * 512),
          16, 0, 0);
    }
  }

  const float* xr = x + (row0 + w * 16 + (L & 15)) * 200;
  const int kg = (L >> 4) * 8;
#pragma unroll
  for (int s = 0; s < 7; ++s) {
    const int k0 = s * 32 + kg;
    bf16x8 v;
    if (k0 < 200) {
      float4 a = *reinterpret_cast<const float4*>(xr + k0);
      float4 b = *reinterpret_cast<const float4*>(xr + k0 + 4);
      v[0] = (bf16_t)a.x; v[1] = (bf16_t)a.y; v[2] = (bf16_t)a.z; v[3] = (bf16_t)a.w;
      v[4] = (bf16_t)b.x; v[5] = (bf16_t)b.y; v[6] = (bf16_t)b.z; v[7] = (bf16_t)b.w;
    } else {
      v[0] = (bf16_t)0.f; v[1] = (bf16_t)0.f; v[2] = (bf16_t)0.f; v[3] = (bf16_t)0.f;
      v[4] = (bf16_t)0.f; v[5] = (bf16_t)0.f; v[6] = (bf16_t)0.f; v[7] = (bf16_t)0.f;
    }
    As[(w * 7 + s) * 64 + L] = v;
  }

  __syncthreads();

  f32x4 acc0 = {0.f, 0.f, 0.f, 0.f};
  f32x4 acc1 = {0.f, 0.f, 0.f, 0.f};
  f32x4 acc2 = {0.f, 0.f, 0.f, 0.f};
  f32x4 acc3 = {0.f, 0.f, 0.f, 0.f};
#pragma unroll
  for (int s = 0; s < 7; ++s) {
    const bf16x8 a = As[(w * 7 + s) * 64 + L];
    acc0 = __builtin_amdgcn_mfma_f32_16x16x32_bf16(a, Bs[(0 * 7 + s) * 64 + L], acc0, 0, 0, 0);
    acc1 = __builtin_amdgcn_mfma_f32_16x16x32_bf16(a, Bs[(1 * 7 + s) * 64 + L], acc1, 0, 0, 0);
    acc2 = __builtin_amdgcn_mfma_f32_16x16x32_bf16(a, Bs[(2 * 7 + s) * 64 + L], acc2, 0, 0, 0);
    acc3 = __builtin_amdgcn_mfma_f32_16x16x32_bf16(a, Bs[(3 * 7 + s) * 64 + L], acc3, 0, 0, 0);
  }

  const int cb = L & 15;
  const float cs = ((cb & 3) == 2) ? (-2.f * LOG2E) : (-LOG2E);
  const long rbase = row0 + w * 16 + ((L >> 4) << 2);
  __bf16* xo = (__bf16*)xproj;
  const float bv0 = biasPerm[ 0 + cb];
  const float bv1 = biasPerm[16 + cb];
  const float bv2 = biasPerm[32 + cb];
  const float bv3 = biasPerm[48 + cb];
#pragma unroll
  for (int q = 0; q < 4; ++q) {
    __bf16* row = xo + (rbase + q) * 64;
    row[ 0 + cb] = (bf16_t)((acc0[q] + bv0) * cs);
    row[16 + cb] = (bf16_t)((acc1[q] + bv1) * cs);
    row[32 + cb] = (bf16_t)((acc2[q] + bv2) * cs);
    row[48 + cb] = (bf16_t)((acc3[q] + bv3) * cs);
  }
}

// ---------------- Kernel 2: LSTM scan (all-gates-in-lane) ----------------
__device__ __forceinline__ void stage_chunk(const unsigned short* g,
                                            unsigned short* l, int lane) {
#pragma unroll
  for (int it = 0; it < 16; ++it) {
    __builtin_amdgcn_global_load_lds(
        (const __attribute__((address_space(1))) unsigned int*)(g + it * 512 + lane * 8),
        (__attribute__((address_space(3))) unsigned int*)(l + it * 512),
        16, 0, 0);
  }
}

// pack h (all lanes hold h[j], j=lane>>2) into 8 wave-uniform f16-pairs
#define PACKH(hval, d0,d1,d2,d3,d4,d5,d6,d7) do {            \
    float _hn = ROWSHL4(hval);                               \
    int _pk = h22i(__builtin_amdgcn_cvt_pkrtz((hval), _hn)); \
    d0 = RDLANE_I(_pk,  0); d1 = RDLANE_I(_pk,  8);          \
    d2 = RDLANE_I(_pk, 16); d3 = RDLANE_I(_pk, 24);          \
    d4 = RDLANE_I(_pk, 32); d5 = RDLANE_I(_pk, 40);          \
    d6 = RDLANE_I(_pk, 48); d7 = RDLANE_I(_pk, 56);          \
  } while (0)

__global__ __launch_bounds__(64, 1) void k2_scan(
    const unsigned short* __restrict__ xproj,
    const float* __restrict__ h0, const float* __restrict__ c0,
    const float* __restrict__ Whh,
    unsigned short* __restrict__ hst)
{
  __shared__ unsigned short xs[2][CHUNK * 64];    // 2 x 16KB
  const int b = blockIdx.x;
  const int lane = threadIdx.x;
  const int j = lane >> 2;

  const unsigned short* gx = xproj + (size_t)b * (T_LEN * 64);
  stage_chunk(gx, xs[0], lane);                   // chunk 0 in flight

  // per-lane weights: ALL 4 gates' Whh rows for this j, f16 pairs, sfac folded
  half2_t wpk[4][8];
#pragma unroll
  for (int gg = 0; gg < 4; ++gg) {
    const int r = (gg << 4) | j;
    const float sf = (gg == 2) ? (-2.f * LOG2E) : (-LOG2E);
#pragma unroll
    for (int q = 0; q < 4; ++q) {
      float4 w = *reinterpret_cast<const float4*>(Whh + r * 16 + q * 4);
      wpk[gg][q * 2 + 0] = __builtin_amdgcn_cvt_pkrtz(w.x * sf, w.y * sf);
      wpk[gg][q * 2 + 1] = __builtin_amdgcn_cvt_pkrtz(w.z * sf, w.w * sf);
    }
  }

  float c = c0[b * 16 + j] * (2.f * LOG2E);       // cell state in exp2 domain
  float hmine = h0[b * 16 + j];
  int hp0, hp1, hp2, hp3, hp4, hp5, hp6, hp7;
  PACKH(hmine, hp0, hp1, hp2, hp3, hp4, hp5, hp6, hp7);

  unsigned short* hq = hst + (size_t)b * (16 * T_LEN) + j * T_LEN;  // [b][j][t]

  __syncthreads();                                // chunk 0 staged

  // 8-deep prefetch of b64 gate-quads (cols 4j..4j+3 = gates 0..3 of j)
  uint2 buf[8];
#pragma unroll
  for (int u = 0; u < 8; ++u)
    buf[u] = *reinterpret_cast<const uint2*>(&xs[0][u * 64 + 4 * j]);

  for (int ch = 0; ch < NCH; ++ch) {
    const unsigned short* xcur = xs[ch & 1];
    if (ch + 1 < NCH) stage_chunk(gx + (ch + 1) * (CHUNK * 64),
                                  (unsigned short*)xs[(ch + 1) & 1], lane);

    for (int ts = 0; ts < CHUNK; ts += 8) {
      float hsv[8];
#pragma unroll
      for (int u = 0; u < 8; ++u) {
        const uint2 d = buf[u];
        int tn = ts + 8 + u;                       // scalar; min avoids vcc
        tn = (tn < CHUNK) ? tn : (CHUNK - 1);
        buf[u] = *reinterpret_cast<const uint2*>(&xcur[tn * 64 + 4 * j]);

        // unpack 4 bf16 gate preacts (sfac pre-folded by k1)
        const float g0 = I2F((int)(d.x << 16));
        const float g1 = I2F((int)(d.x & 0xffff0000u));
        const float g2 = I2F((int)(d.y << 16));
        const float g3 = I2F((int)(d.y & 0xffff0000u));

        // 4 gate dots, each 2 chains of 4 fdot2 + 1 add (all in-lane)
        float a0 = FDOT2(wpk[0][0], i2h2(hp0), g0);
        a0 = FDOT2(wpk[0][1], i2h2(hp1), a0);
        a0 = FDOT2(wpk[0][2], i2h2(hp2), a0);
        a0 = FDOT2(wpk[0][3], i2h2(hp3), a0);
        float c0d = FDOT2(wpk[0][4], i2h2(hp4), 0.f);
        c0d = FDOT2(wpk[0][5], i2h2(hp5), c0d);
        c0d = FDOT2(wpk[0][6], i2h2(hp6), c0d);
        c0d = FDOT2(wpk[0][7], i2h2(hp7), c0d);
        const float p0 = a0 + c0d;

        float a1 = FDOT2(wpk[1][0], i2h2(hp0), g1);
        a1 = FDOT2(wpk[1][1], i2h2(hp1), a1);
        a1 = FDOT2(wpk[1][2], i2h2(hp2), a1);
        a1 = FDOT2(wpk[1][3], i2h2(hp3), a1);
        float c1d = FDOT2(wpk[1][4], i2h2(hp4), 0.f);
        c1d = FDOT2(wpk[1][5], i2h2(hp5), c1d);
        c1d = FDOT2(wpk[1][6], i2h2(hp6), c1d);
        c1d = FDOT2(wpk[1][7], i2h2(hp7), c1d);
        const float p1 = a1 + c1d;

        float a2 = FDOT2(wpk[2][0], i2h2(hp0), g2);
        a2 = FDOT2(wpk[2][1], i2h2(hp1), a2);
        a2 = FDOT2(wpk[2][2], i2h2(hp2), a2);
        a2 = FDOT2(wpk[2][3], i2h2(hp3), a2);
        float c2d = FDOT2(wpk[2][4], i2h2(hp4), 0.f);
        c2d = FDOT2(wpk[2][5], i2h2(hp5), c2d);
        c2d = FDOT2(wpk[2][6], i2h2(hp6), c2d);
        c2d = FDOT2(wpk[2][7], i2h2(hp7), c2d);
        const float p2 = a2 + c2d;

        float a3 = FDOT2(wpk[3][0], i2h2(hp0), g3);
        a3 = FDOT2(wpk[3][1], i2h2(hp1), a3);
        a3 = FDOT2(wpk[3][2], i2h2(hp2), a3);
        a3 = FDOT2(wpk[3][3], i2h2(hp3), a3);
        float c3d = FDOT2(wpk[3][4], i2h2(hp4), 0.f);
        c3d = FDOT2(wpk[3][5], i2h2(hp5), c3d);
        c3d = FDOT2(wpk[3][6], i2h2(hp6), c3d);
        c3d = FDOT2(wpk[3][7], i2h2(hp7), c3d);
        const float p3 = a3 + c3d;

        // activations (all in-lane, no DPP)
        const float z0 = frcp(1.f + fexp2(p0));   // sigmoid(i)
        const float z1 = frcp(1.f + fexp2(p1));   // sigmoid(f)
        const float z2 = frcp(1.f + fexp2(p2));   // (tanh(g)+1)/2
        const float z3 = frcp(1.f + fexp2(p3));   // sigmoid(o)

        const float yi = (2.f * LOG2E) * z0;      // i pre-scaled for exp2-domain c
        const float gt = fmaf(2.f, z2, -1.f);     // tanh(g)
        c = fmaf(z1, c, yi * gt);                 // scaled cell state

        const float e2x = fexp2(c);               // e^{2 c_true}
        const float th = fmaf(-2.f, frcp(1.f + e2x), 1.f);  // tanh(c_true)
        const float h = z3 * th;

        PACKH(h, hp0, hp1, hp2, hp3, hp4, hp5, hp6, hp7);
        hsv[u] = h;
      }
      if ((lane & 3) == 0) {                      // one 16B store per 8 steps
        uint4 pk;
        pk.x = pkbf(hsv[0], hsv[1]);
        pk.y = pkbf(hsv[2], hsv[3]);
        pk.z = pkbf(hsv[4], hsv[5]);
        pk.w = pkbf(hsv[6], hsv[7]);
        *reinterpret_cast<uint4*>(hq + ch * CHUNK + ts) = pk;
      }
    }

    __syncthreads();                              // next chunk staged
    if (ch + 1 < NCH) {
      const unsigned short* xn = xs[(ch + 1) & 1];
#pragma unroll
      for (int u = 0; u < 8; ++u)
        buf[u] = *reinterpret_cast<const uint2*>(&xn[u * 64 + 4 * j]);
    }
  }
}

// ---------------- Kernel 3: head + mean (hst layout [b][j][t]) ----------------
__global__ __launch_bounds__(256) void k3_head(
    const unsigned short* __restrict__ hst,
    const float* __restrict__ W1, const float* __restrict__ b1,
    const float* __restrict__ W2, const float* __restrict__ b2,
    float* __restrict__ out)
{
  __shared__ float ws1[256];
  __shared__ float wsb1[16], wsw2[16];
  __shared__ float red[256];
  const int tid = threadIdx.x;
  const int b = blockIdx.x;

  ws1[tid] = W1[tid];
  if (tid < 16) { wsb1[tid] = b1[tid]; wsw2[tid] = W2[tid]; }
  __syncthreads();
  const float b2s = b2[0];

  const unsigned short* hb = hst + (size_t)b * (16 * T_LEN);
  float acc = 0.f;
#pragma unroll
  for (int it = 0; it < 2; ++it) {
    const int t2 = it * 256 + tid;               // pair index, t = 2*t2
    unsigned int hp[16];
#pragma unroll
    for (int jj = 0; jj < 16; ++jj)
      hp[jj] = *reinterpret_cast<const unsigned int*>(hb + jj * T_LEN + 2 * t2);
    float h0v[16], h1v[16];
#pragma unroll
    for (int k = 0; k < 16; ++k) {
      h0v[k] = bf2f((unsigned short)(hp[k] & 0xffff));
      h1v[k] = bf2f((unsigned short)(hp[k] >> 16));
    }
    float s0 = b2s, s1 = b2s;
#pragma unroll
    for (int jj = 0; jj < 16; ++jj) {
      float p0 = wsb1[jj], p1 = wsb1[jj];
#pragma unroll
      for (int k = 0; k < 16; ++k) {
        const float wv = ws1[jj * 16 + k];
        p0 = fmaf(wv, h0v[k], p0);
        p1 = fmaf(wv, h1v[k], p1);
      }
      p0 = fmaxf(p0, 0.f);
      p1 = fmaxf(p1, 0.f);
      s0 = fmaf(wsw2[jj], p0, s0);
      s1 = fmaf(wsw2[jj], p1, s1);
    }
    acc += frcp(1.f + fexp2(-LOG2E * s0));
    acc += frcp(1.f + fexp2(-LOG2E * s1));
  }

  red[tid] = acc;
  __syncthreads();
  if (tid < 128) red[tid] += red[tid + 128];
  __syncthreads();
  if (tid < 64) {
    float v = red[tid] + red[tid + 64];
    v += __shfl_xor(v, 32, 64);
    v += __shfl_xor(v, 16, 64);
    v += __shfl_xor(v, 8, 64);
    v += __shfl_xor(v, 4, 64);
    v += __shfl_xor(v, 2, 64);
    v += __shfl_xor(v, 1, 64);
    if (tid == 0) out[b] = v * (1.f / T_LEN);
  }
}

// ---------------- launcher ----------------
extern "C" void kernel_launch(void* const* d_in, const int* in_sizes, int n_in,
                              void* d_out, int out_size, void* d_ws, size_t ws_size,
                              hipStream_t stream) {
  const float* x   = (const float*)d_in[0];
  const float* h0  = (const float*)d_in[1];
  const float* c0  = (const float*)d_in[2];
  const float* Wih = (const float*)d_in[3];
  const float* Whh = (const float*)d_in[4];
  const float* bih = (const float*)d_in[5];
  const float* bhh = (const float*)d_in[6];
  const float* W1  = (const float*)d_in[7];
  const float* b1  = (const float*)d_in[8];
  const float* W2  = (const float*)d_in[9];
  const float* b2  = (const float*)d_in[10];

  char* wsb = (char*)d_ws;
  unsigned short* xproj = (unsigned short*)wsb;                     // 32 MiB
  unsigned short* hst   = (unsigned short*)(wsb + 33554432);        // 8 MiB
  bf16x8* wB            = (bf16x8*)(wsb + 33554432 + 8388608);      // 28 KiB
  float* biasPerm       = (float*)(wsb + 33554432 + 8388608 + 32768);

  hipLaunchKernelGGL(k0_prep, dim3(7), dim3(256), 0, stream,
                     Wih, bih, bhh, wB, biasPerm);
  hipLaunchKernelGGL(k1_xproj, dim3(4096), dim3(256), 0, stream,
                     x, wB, biasPerm, xproj);
  hipLaunchKernelGGL(k2_scan, dim3(NB), dim3(64), 0, stream,
                     xproj, h0, c0, Whh, hst);
  hipLaunchKernelGGL(k3_head, dim3(NB), dim3(256), 0, stream,
                     hst, W1, b1, W2, b2, (float*)d_out);
}

// Round 13
// 134.334 us; speedup vs baseline: 1.6829x; 1.6829x over previous
//
#include <hip/hip_runtime.h>

// LSTMDiscriminator: B=256, T=1024, I=200, H=16
// K0: prepack W_ih (permuted cols, bf16, fragment-linear) + fused bias -> ws
// MEGA: one block per batch (256 threads = 4 waves), barrier-phased pipeline.
//   wave 0   = LSTM scanner — EXACT R11 body (proven 125us standalone)
//   waves1-3 = MFMA producers: B-frags from LDS (k1-proven), A-frags direct
//              to VGPRs (static unroll, ~80 VGPR, NO spill), bf16 -> xs LDS.
//   10 matched __syncthreads per wave; no atomics, no polling.
// K3: head relu(h@W1^T+b1)@W2^T+b2 -> sigmoid -> mean over T (hst [b][j][t]).

#define T_LEN 1024
#define NB    256
#define CHUNK 128
#define NCH   (T_LEN / CHUNK)

#define F2I(x) __float_as_int(x)
#define I2F(x) __int_as_float(x)
// row_shl:4 (0x104): lane i reads lane i+4 -> brings h_{j+1} to quad j
#define ROWSHL4(v) I2F(__builtin_amdgcn_update_dpp(F2I(v), F2I(v), 0x104, 0xF, 0xF, false))
#define DPPF(v, ctrl) I2F(__builtin_amdgcn_update_dpp(F2I(v), F2I(v), (ctrl), 0xF, 0xF, false))
#define RDLANE_I(v, l) __builtin_amdgcn_readlane((v), (l))

#define LOG2E 1.442695040888963f

typedef __bf16 bf16_t;
typedef bf16_t bf16x8 __attribute__((ext_vector_type(8)));
typedef float f32x4 __attribute__((ext_vector_type(4)));
typedef __fp16 half2_t __attribute__((ext_vector_type(2)));

#if __has_builtin(__builtin_amdgcn_exp2f)
__device__ __forceinline__ float fexp2(float x) { return __builtin_amdgcn_exp2f(x); }
#else
__device__ __forceinline__ float fexp2(float x) { return exp2f(x); }
#endif
#if __has_builtin(__builtin_amdgcn_rcpf)
__device__ __forceinline__ float frcp(float x) { return __builtin_amdgcn_rcpf(x); }
#else
__device__ __forceinline__ float frcp(float x) { return __fdividef(1.f, x); }
#endif

__device__ __forceinline__ half2_t i2h2(int x) { union { int i; half2_t h; } u; u.i = x; return u.h; }
__device__ __forceinline__ int h22i(half2_t h) { union { int i; half2_t h; } u; u.h = h; return u.i; }

#if __has_builtin(__builtin_amdgcn_fdot2)
#define FDOT2(a, b, c) __builtin_amdgcn_fdot2((a), (b), (c), false)
#else
__device__ __forceinline__ float FDOT2(half2_t a, half2_t b, float c) {
  return c + (float)a[0] * (float)b[0] + (float)a[1] * (float)b[1];
}
#endif

__device__ __forceinline__ float bf2f(unsigned short s) {
  return __uint_as_float(((unsigned int)s) << 16);
}
__device__ __forceinline__ unsigned int pkbf(float a, float b) {
  bf16_t x = (bf16_t)a, y = (bf16_t)b;
  unsigned short ux, uy;
  __builtin_memcpy(&ux, &x, 2); __builtin_memcpy(&uy, &y, 2);
  return (unsigned int)ux | ((unsigned int)uy << 16);
}

// ---------------- Kernel 0: prepack W (bf16, fragment-linear) + bias ----------------
__global__ __launch_bounds__(256) void k0_prep(
    const float* __restrict__ Wih, const float* __restrict__ bih,
    const float* __restrict__ bhh, bf16x8* __restrict__ wB,
    float* __restrict__ biasPerm)
{
  const int idx = blockIdx.x * 256 + threadIdx.x;   // 0..1791
  if (idx < 4 * 7 * 64) {
    const int f = idx / 448;
    const int rem = idx % 448;
    const int s = rem / 64;
    const int L = rem % 64;
    const int col = f * 16 + (L & 15);
    const int r = ((col & 3) << 4) | (col >> 2);
    const int k0 = s * 32 + (L >> 4) * 8;
    bf16x8 v;
#pragma unroll
    for (int e = 0; e < 8; ++e) {
      const int k = k0 + e;
      const float w = (k < 200) ? Wih[r * 200 + k] : 0.f;
      v[e] = (bf16_t)w;
    }
    wB[idx] = v;
  }
  if (blockIdx.x == 0 && threadIdx.x < 64) {
    const int c = threadIdx.x;
    const int r = ((c & 3) << 4) | (c >> 2);
    biasPerm[c] = bih[r] + bhh[r];
  }
}

// pack h (quad-uniform) into 8 wave-uniform f16-pairs
#define PACKH(hval, d0,d1,d2,d3,d4,d5,d6,d7) do {            \
    float _hn = ROWSHL4(hval);                               \
    int _pk = h22i(__builtin_amdgcn_cvt_pkrtz((hval), _hn)); \
    d0 = RDLANE_I(_pk,  0); d1 = RDLANE_I(_pk,  8);          \
    d2 = RDLANE_I(_pk, 16); d3 = RDLANE_I(_pk, 24);          \
    d4 = RDLANE_I(_pk, 32); d5 = RDLANE_I(_pk, 40);          \
    d6 = RDLANE_I(_pk, 48); d7 = RDLANE_I(_pk, 56);          \
  } while (0)

// ---------------- MEGA kernel ----------------
__global__ __launch_bounds__(256, 1) void mega(
    const float* __restrict__ x,
    const bf16x8* __restrict__ wB, const float* __restrict__ biasPerm,
    const float* __restrict__ h0, const float* __restrict__ c0,
    const float* __restrict__ Whh,
    unsigned short* __restrict__ hst)
{
  __shared__ unsigned short xs[2][CHUNK * 64];  // 2 x 16 KB, bf16 (sfac folded)
  __shared__ bf16x8 Bs[28 * 64];                // 28 KB, fragment-linear W

  const int tid  = threadIdx.x;
  const int lane = tid & 63;
  const int wid  = tid >> 6;
  const int b    = blockIdx.x;

  if (wid != 0) {
    // ================= producer waves (1..3) =================
    const int pw   = wid - 1;            // 0..2
    const int L    = lane;
    const int mrow = L & 15;
    const int kg   = L >> 4;             // 0..3
    const int cb   = L & 15;

    // stage Bs once (28 KB split across 3 waves)
    {
      const unsigned short* src = (const unsigned short*)wB;
      unsigned short* dst = (unsigned short*)Bs;
      for (int it = pw; it < 28; it += 3) {
        __builtin_amdgcn_global_load_lds(
            (const __attribute__((address_space(1))) unsigned int*)(src + it * 512 + L * 8),
            (__attribute__((address_space(3))) unsigned int*)(dst + it * 512),
            16, 0, 0);
      }
    }

    const float bv0 = biasPerm[ 0 + cb];
    const float bv1 = biasPerm[16 + cb];
    const float bv2 = biasPerm[32 + cb];
    const float bv3 = biasPerm[48 + cb];
    const float cs  = ((cb & 3) == 2) ? (-2.f * LOG2E) : (-LOG2E);

    auto produce = [&](int pc) {
      for (int t8 = pw; t8 < 8; t8 += 3) {          // this wave's tiles
        const int tile = pc * 8 + t8;
        const float* xr = x + ((size_t)b * T_LEN + tile * 16 + mrow) * 200;
        bf16x8 afr[7];                               // static full unroll
#pragma unroll
        for (int s = 0; s < 7; ++s) {
          const int k0 = s * 32 + kg * 8;
          bf16x8 v;
          if (k0 <= 192) {
            float4 a  = *reinterpret_cast<const float4*>(xr + k0);
            float4 b4 = *reinterpret_cast<const float4*>(xr + k0 + 4);
            v[0] = (bf16_t)a.x;  v[1] = (bf16_t)a.y;  v[2] = (bf16_t)a.z;  v[3] = (bf16_t)a.w;
            v[4] = (bf16_t)b4.x; v[5] = (bf16_t)b4.y; v[6] = (bf16_t)b4.z; v[7] = (bf16_t)b4.w;
          } else {
            v[0] = (bf16_t)0.f; v[1] = (bf16_t)0.f; v[2] = (bf16_t)0.f; v[3] = (bf16_t)0.f;
            v[4] = (bf16_t)0.f; v[5] = (bf16_t)0.f; v[6] = (bf16_t)0.f; v[7] = (bf16_t)0.f;
          }
          afr[s] = v;
        }

        f32x4 acc0 = {0.f,0.f,0.f,0.f}, acc1 = {0.f,0.f,0.f,0.f};
        f32x4 acc2 = {0.f,0.f,0.f,0.f}, acc3 = {0.f,0.f,0.f,0.f};
#pragma unroll
        for (int s = 0; s < 7; ++s) {                // B from LDS (k1-proven)
          acc0 = __builtin_amdgcn_mfma_f32_16x16x32_bf16(afr[s], Bs[(0*7+s)*64 + L], acc0, 0,0,0);
          acc1 = __builtin_amdgcn_mfma_f32_16x16x32_bf16(afr[s], Bs[(1*7+s)*64 + L], acc1, 0,0,0);
          acc2 = __builtin_amdgcn_mfma_f32_16x16x32_bf16(afr[s], Bs[(2*7+s)*64 + L], acc2, 0,0,0);
          acc3 = __builtin_amdgcn_mfma_f32_16x16x32_bf16(afr[s], Bs[(3*7+s)*64 + L], acc3, 0,0,0);
        }

        // C/D: col = lane&15, row = (lane>>4)*4 + q. Write bf16 (sfac folded).
        __bf16* dst = (__bf16*)&xs[pc & 1][(t8 * 16) * 64];
#pragma unroll
        for (int q = 0; q < 4; ++q) {
          __bf16* rowp = dst + (kg * 4 + q) * 64;
          rowp[ 0 + cb] = (bf16_t)((acc0[q] + bv0) * cs);
          rowp[16 + cb] = (bf16_t)((acc1[q] + bv1) * cs);
          rowp[32 + cb] = (bf16_t)((acc2[q] + bv2) * cs);
          rowp[48 + cb] = (bf16_t)((acc3[q] + bv3) * cs);
        }
      }
    };

    __syncthreads();                     // #1: Bs staged (own vmcnt drained)
    produce(0);
    for (int ch = 0; ch < NCH; ++ch) {
      __syncthreads();                   // #2..#9: chunk ch ready
      if (ch + 1 < NCH) produce(ch + 1);
    }
    __syncthreads();                     // #10: matches scanner's final
    return;
  }

  // ================= scanner wave (wave 0) — EXACT R11 body =================
  __builtin_amdgcn_s_setprio(1);
  const int g = lane & 3;
  const int j = lane >> 2;
  const int r = (g << 4) | j;

  const float sfac = (g == 2) ? (-2.f * LOG2E) : (-LOG2E);
  const float pfac = (g == 0) ? (2.f * LOG2E) : ((g == 2) ? 2.f : 1.f);
  const float qfac = (g == 2) ? -1.f : 0.f;

  half2_t wpk[8];
#pragma unroll
  for (int q = 0; q < 4; ++q) {
    float4 w = *reinterpret_cast<const float4*>(Whh + r * 16 + q * 4);
    wpk[q * 2 + 0] = __builtin_amdgcn_cvt_pkrtz(w.x * sfac, w.y * sfac);
    wpk[q * 2 + 1] = __builtin_amdgcn_cvt_pkrtz(w.z * sfac, w.w * sfac);
  }

  float c = c0[b * 16 + j] * (2.f * LOG2E);       // cell state in exp2 domain
  float hmine = h0[b * 16 + j];                   // quad-uniform
  int hp0, hp1, hp2, hp3, hp4, hp5, hp6, hp7;
  PACKH(hmine, hp0, hp1, hp2, hp3, hp4, hp5, hp6, hp7);

  unsigned short* hq = hst + (size_t)b * (16 * T_LEN) + j * T_LEN;  // [b][j][t]

  __syncthreads();                                // #1
  __syncthreads();                                // #2: chunk 0 ready

  float buf[8];
#pragma unroll
  for (int u = 0; u < 8; ++u)
    buf[u] = bf2f(xs[0][u * 64 + lane]);          // sfac pre-folded by producer

  for (int ch = 0; ch < NCH; ++ch) {
    const unsigned short* xcur = xs[ch & 1];

    for (int ts = 0; ts < CHUNK; ts += 8) {
      float hsv[8];
#pragma unroll
      for (int u = 0; u < 8; ++u) {
        const float gin = buf[u];
        int tn = ts + 8 + u;
        tn = (tn < CHUNK) ? tn : (CHUNK - 1);     // clamped dummy reload at tail
        buf[u] = bf2f(xcur[tn * 64 + lane]);

        // pre = sfac*(Wx+b + Whh h): 4 chains of 2 dot2 + add tree
        float e0 = FDOT2(wpk[0], i2h2(hp0), gin);
        e0 = FDOT2(wpk[1], i2h2(hp1), e0);
        float e1 = FDOT2(wpk[2], i2h2(hp2), 0.f);
        e1 = FDOT2(wpk[3], i2h2(hp3), e1);
        float e2 = FDOT2(wpk[4], i2h2(hp4), 0.f);
        e2 = FDOT2(wpk[5], i2h2(hp5), e2);
        float e3 = FDOT2(wpk[6], i2h2(hp6), 0.f);
        e3 = FDOT2(wpk[7], i2h2(hp7), e3);
        float pre = (e0 + e1) + (e2 + e3);

        float e = fexp2(pre);
        float z = frcp(1.f + e);
        float y = fmaf(pfac, z, qfac);  // g0: 2log2e*i, g1: f, g2: tanh g, g3: o

        // c' = f*c' + (2log2e*i)*g via quad DPP combine (3 DPP total)
        float t1 = DPPF(y, 0x4E) * y;             // lane0: g*(2log2e*i)
        float ig = DPPF(t1, 0x00);                // broadcast lane0 to quad
        c = fmaf(DPPF(y, 0x55), c, ig);           // f from lane1

        float e2x = fexp2(c);                     // e^{2*c_true}
        float z2 = frcp(1.f + e2x);
        float th = fmaf(-2.f, z2, 1.f);           // tanh(c_true)
        float h = DPPF(y, 0xFF) * th;             // o from lane3; quad-uniform

        PACKH(h, hp0, hp1, hp2, hp3, hp4, hp5, hp6, hp7);
        hsv[u] = h;
      }
      if (g == 0) {                               // one 16B store per 8 steps
        uint4 pk;
        pk.x = pkbf(hsv[0], hsv[1]);
        pk.y = pkbf(hsv[2], hsv[3]);
        pk.z = pkbf(hsv[4], hsv[5]);
        pk.w = pkbf(hsv[6], hsv[7]);
        *reinterpret_cast<uint4*>(hq + ch * CHUNK + ts) = pk;
      }
    }

    __syncthreads();                              // #(3+ch): next chunk ready
    if (ch + 1 < NCH) {
      const unsigned short* xn = xs[(ch + 1) & 1];
#pragma unroll
      for (int u = 0; u < 8; ++u) buf[u] = bf2f(xn[u * 64 + lane]);
    }
  }
}

// ---------------- Kernel 3: head + mean (hst layout [b][j][t]) ----------------
__global__ __launch_bounds__(256) void k3_head(
    const unsigned short* __restrict__ hst,
    const float* __restrict__ W1, const float* __restrict__ b1,
    const float* __restrict__ W2, const float* __restrict__ b2,
    float* __restrict__ out)
{
  __shared__ float ws1[256];
  __shared__ float wsb1[16], wsw2[16];
  __shared__ float red[256];
  const int tid = threadIdx.x;
  const int b = blockIdx.x;

  ws1[tid] = W1[tid];
  if (tid < 16) { wsb1[tid] = b1[tid]; wsw2[tid] = W2[tid]; }
  __syncthreads();
  const float b2s = b2[0];

  const unsigned short* hb = hst + (size_t)b * (16 * T_LEN);
  float acc = 0.f;
#pragma unroll
  for (int it = 0; it < 2; ++it) {
    const int t2 = it * 256 + tid;               // pair index, t = 2*t2
    unsigned int hp[16];
#pragma unroll
    for (int jj = 0; jj < 16; ++jj)
      hp[jj] = *reinterpret_cast<const unsigned int*>(hb + jj * T_LEN + 2 * t2);
    float h0v[16], h1v[16];
#pragma unroll
    for (int k = 0; k < 16; ++k) {
      h0v[k] = bf2f((unsigned short)(hp[k] & 0xffff));
      h1v[k] = bf2f((unsigned short)(hp[k] >> 16));
    }
    float s0 = b2s, s1 = b2s;
#pragma unroll
    for (int jj = 0; jj < 16; ++jj) {
      float p0 = wsb1[jj], p1 = wsb1[jj];
#pragma unroll
      for (int k = 0; k < 16; ++k) {
        const float wv = ws1[jj * 16 + k];
        p0 = fmaf(wv, h0v[k], p0);
        p1 = fmaf(wv, h1v[k], p1);
      }
      p0 = fmaxf(p0, 0.f);
      p1 = fmaxf(p1, 0.f);
      s0 = fmaf(wsw2[jj], p0, s0);
      s1 = fmaf(wsw2[jj], p1, s1);
    }
    acc += frcp(1.f + fexp2(-LOG2E * s0));
    acc += frcp(1.f + fexp2(-LOG2E * s1));
  }

  red[tid] = acc;
  __syncthreads();
  if (tid < 128) red[tid] += red[tid + 128];
  __syncthreads();
  if (tid < 64) {
    float v = red[tid] + red[tid + 64];
    v += __shfl_xor(v, 32, 64);
    v += __shfl_xor(v, 16, 64);
    v += __shfl_xor(v, 8, 64);
    v += __shfl_xor(v, 4, 64);
    v += __shfl_xor(v, 2, 64);
    v += __shfl_xor(v, 1, 64);
    if (tid == 0) out[b] = v * (1.f / T_LEN);
  }
}

// ---------------- launcher ----------------
extern "C" void kernel_launch(void* const* d_in, const int* in_sizes, int n_in,
                              void* d_out, int out_size, void* d_ws, size_t ws_size,
                              hipStream_t stream) {
  const float* x   = (const float*)d_in[0];
  const float* h0  = (const float*)d_in[1];
  const float* c0  = (const float*)d_in[2];
  const float* Wih = (const float*)d_in[3];
  const float* Whh = (const float*)d_in[4];
  const float* bih = (const float*)d_in[5];
  const float* bhh = (const float*)d_in[6];
  const float* W1  = (const float*)d_in[7];
  const float* b1  = (const float*)d_in[8];
  const float* W2  = (const float*)d_in[9];
  const float* b2  = (const float*)d_in[10];

  char* wsb = (char*)d_ws;
  unsigned short* hst = (unsigned short*)wsb;                 // 8 MiB
  bf16x8* wB          = (bf16x8*)(wsb + 8388608);             // 28 KiB
  float* biasPerm     = (float*)(wsb + 8388608 + 32768);      // 256 B

  hipLaunchKernelGGL(k0_prep, dim3(7), dim3(256), 0, stream,
                     Wih, bih, bhh, wB, biasPerm);
  hipLaunchKernelGGL(mega, dim3(NB), dim3(256), 0, stream,
                     x, wB, biasPerm, h0, c0, Whh, hst);
  hipLaunchKernelGGL(k3_head, dim3(NB), dim3(256), 0, stream,
                     hst, W1, b1, W2, b2, (float*)d_out);
}

// Round 14
// 132.555 us; speedup vs baseline: 1.7054x; 1.0134x over previous
//
#include <hip/hip_runtime.h>

// LSTMDiscriminator: B=256, T=1024, I=200, H=16 — single fused kernel.
// MEGA: one block per batch (256 threads = 4 waves), barrier-phased pipeline.
//   wave 0   = LSTM scanner (R11 body, proven 125us): fdot2 recurrent dot,
//              exp2-domain cell state, h history -> LDS hstL.
//   waves1-3 = MFMA producers: inline-convert W_ih -> Bs (LDS), A-frags direct
//              to VGPRs (static unroll, no spill), bf16 preacts -> xs LDS
//              (rows padded to 68 ushorts: conflict-free stores).
//   then all 4 waves: head relu(h@W1^T+b1)@W2^T+b2 -> sigmoid -> mean -> out.
// Sync: matched __syncthreads pipeline; no atomics, no polling, no scratch ws.

#define T_LEN 1024
#define NB    256
#define CHUNK 128
#define NCH   (T_LEN / CHUNK)
#define XSTR  68               // xs row stride in ushorts (bank-conflict-free)
#define HSTR  1032             // hstL row stride in ushorts (pad 8)

#define F2I(x) __float_as_int(x)
#define I2F(x) __int_as_float(x)
#define DPPF(v, ctrl) I2F(__builtin_amdgcn_update_dpp(F2I(v), F2I(v), (ctrl), 0xF, 0xF, false))
// row_shl:4 (0x104): lane i reads lane i+4 -> brings h_{j+1} to quad j
#define ROWSHL4(v) I2F(__builtin_amdgcn_update_dpp(F2I(v), F2I(v), 0x104, 0xF, 0xF, false))
#define RDLANE_I(v, l) __builtin_amdgcn_readlane((v), (l))

#define LOG2E 1.442695040888963f

typedef __bf16 bf16_t;
typedef bf16_t bf16x8 __attribute__((ext_vector_type(8)));
typedef float f32x4 __attribute__((ext_vector_type(4)));
typedef __fp16 half2_t __attribute__((ext_vector_type(2)));

#if __has_builtin(__builtin_amdgcn_exp2f)
__device__ __forceinline__ float fexp2(float x) { return __builtin_amdgcn_exp2f(x); }
#else
__device__ __forceinline__ float fexp2(float x) { return exp2f(x); }
#endif
#if __has_builtin(__builtin_amdgcn_rcpf)
__device__ __forceinline__ float frcp(float x) { return __builtin_amdgcn_rcpf(x); }
#else
__device__ __forceinline__ float frcp(float x) { return __fdividef(1.f, x); }
#endif

__device__ __forceinline__ half2_t i2h2(int x) { union { int i; half2_t h; } u; u.i = x; return u.h; }
__device__ __forceinline__ int h22i(half2_t h) { union { int i; half2_t h; } u; u.h = h; return u.i; }

#if __has_builtin(__builtin_amdgcn_fdot2)
#define FDOT2(a, b, c) __builtin_amdgcn_fdot2((a), (b), (c), false)
#else
__device__ __forceinline__ float FDOT2(half2_t a, half2_t b, float c) {
  return c + (float)a[0] * (float)b[0] + (float)a[1] * (float)b[1];
}
#endif

__device__ __forceinline__ float bf2f(unsigned short s) {
  return __uint_as_float(((unsigned int)s) << 16);
}
__device__ __forceinline__ unsigned int pkbf(float a, float b) {
  bf16_t x = (bf16_t)a, y = (bf16_t)b;
  unsigned short ux, uy;
  __builtin_memcpy(&ux, &x, 2); __builtin_memcpy(&uy, &y, 2);
  return (unsigned int)ux | ((unsigned int)uy << 16);
}

// pack h (quad-uniform) into 8 wave-uniform f16-pairs
#define PACKH(hval, d0,d1,d2,d3,d4,d5,d6,d7) do {            \
    float _hn = ROWSHL4(hval);                               \
    int _pk = h22i(__builtin_amdgcn_cvt_pkrtz((hval), _hn)); \
    d0 = RDLANE_I(_pk,  0); d1 = RDLANE_I(_pk,  8);          \
    d2 = RDLANE_I(_pk, 16); d3 = RDLANE_I(_pk, 24);          \
    d4 = RDLANE_I(_pk, 32); d5 = RDLANE_I(_pk, 40);          \
    d6 = RDLANE_I(_pk, 48); d7 = RDLANE_I(_pk, 56);          \
  } while (0)

// ---------------- MEGA kernel ----------------
__global__ __launch_bounds__(256, 1) void mega(
    const float* __restrict__ x,
    const float* __restrict__ Wih, const float* __restrict__ bih,
    const float* __restrict__ bhh,
    const float* __restrict__ h0, const float* __restrict__ c0,
    const float* __restrict__ Whh,
    const float* __restrict__ W1, const float* __restrict__ b1,
    const float* __restrict__ W2, const float* __restrict__ b2,
    float* __restrict__ out)
{
  __shared__ unsigned short xs[2][CHUNK * XSTR];  // 2 x 17408 B, bf16 preacts
  __shared__ bf16x8 Bs[28 * 64];                  // 28 KB fragment-linear W
  __shared__ __attribute__((aligned(16))) unsigned short hstL[16 * HSTR]; // 33024 B
  __shared__ float ws1[256];
  __shared__ float wsb1[16], wsw2[16];
  __shared__ float red[256];

  const int tid  = threadIdx.x;
  const int lane = tid & 63;
  const int wid  = tid >> 6;
  const int b    = blockIdx.x;

  // prologue (all threads, before any barrier): head weights -> LDS
  ws1[tid] = W1[tid];
  if (tid < 16) { wsb1[tid] = b1[tid]; wsw2[tid] = W2[tid]; }
  const float b2s = b2[0];

  if (wid != 0) {
    // ================= producer waves (1..3) =================
    const int pw   = wid - 1;            // 0..2
    const int L    = lane;
    const int mrow = L & 15;
    const int kg   = L >> 4;             // 0..3
    const int cb   = L & 15;

    // --- inline k0: convert W_ih -> fragment-linear bf16 in Bs ---
    // fragment (f,s): lane L holds B[k = s*32+(L>>4)*8+e][col = f*16+(L&15)]
    for (int i = pw; i < 28; i += 3) {
      const int f = i / 7;
      const int s = i % 7;
      const int col = f * 16 + cb;
      const int r = ((col & 3) << 4) | (col >> 2);
      const int k0 = s * 32 + kg * 8;
      bf16x8 v;
      if (k0 <= 192) {                   // k0=192 reads 192..199 exactly
        float4 a  = *reinterpret_cast<const float4*>(Wih + r * 200 + k0);
        float4 b4 = *reinterpret_cast<const float4*>(Wih + r * 200 + k0 + 4);
        v[0] = (bf16_t)a.x;  v[1] = (bf16_t)a.y;  v[2] = (bf16_t)a.z;  v[3] = (bf16_t)a.w;
        v[4] = (bf16_t)b4.x; v[5] = (bf16_t)b4.y; v[6] = (bf16_t)b4.z; v[7] = (bf16_t)b4.w;
      } else {
        v[0] = (bf16_t)0.f; v[1] = (bf16_t)0.f; v[2] = (bf16_t)0.f; v[3] = (bf16_t)0.f;
        v[4] = (bf16_t)0.f; v[5] = (bf16_t)0.f; v[6] = (bf16_t)0.f; v[7] = (bf16_t)0.f;
      }
      Bs[i * 64 + L] = v;
    }

    // --- inline bias: bv_f for col f*16+cb ---
    float bv[4];
#pragma unroll
    for (int f = 0; f < 4; ++f) {
      const int r = ((cb & 3) << 4) | (4 * f + (cb >> 2));
      bv[f] = bih[r] + bhh[r];
    }
    const float cs = ((cb & 3) == 2) ? (-2.f * LOG2E) : (-LOG2E);

    auto produce = [&](int pc) {
      for (int t8 = pw; t8 < 8; t8 += 3) {
        const int tile = pc * 8 + t8;
        const float* xr = x + ((size_t)b * T_LEN + tile * 16 + mrow) * 200;
        bf16x8 afr[7];                   // static full unroll, no spill
#pragma unroll
        for (int s = 0; s < 7; ++s) {
          const int k0 = s * 32 + kg * 8;
          bf16x8 v;
          if (k0 <= 192) {
            float4 a  = *reinterpret_cast<const float4*>(xr + k0);
            float4 b4 = *reinterpret_cast<const float4*>(xr + k0 + 4);
            v[0] = (bf16_t)a.x;  v[1] = (bf16_t)a.y;  v[2] = (bf16_t)a.z;  v[3] = (bf16_t)a.w;
            v[4] = (bf16_t)b4.x; v[5] = (bf16_t)b4.y; v[6] = (bf16_t)b4.z; v[7] = (bf16_t)b4.w;
          } else {
            v[0] = (bf16_t)0.f; v[1] = (bf16_t)0.f; v[2] = (bf16_t)0.f; v[3] = (bf16_t)0.f;
            v[4] = (bf16_t)0.f; v[5] = (bf16_t)0.f; v[6] = (bf16_t)0.f; v[7] = (bf16_t)0.f;
          }
          afr[s] = v;
        }

        f32x4 acc0 = {0.f,0.f,0.f,0.f}, acc1 = {0.f,0.f,0.f,0.f};
        f32x4 acc2 = {0.f,0.f,0.f,0.f}, acc3 = {0.f,0.f,0.f,0.f};
#pragma unroll
        for (int s = 0; s < 7; ++s) {
          acc0 = __builtin_amdgcn_mfma_f32_16x16x32_bf16(afr[s], Bs[(0*7+s)*64 + L], acc0, 0,0,0);
          acc1 = __builtin_amdgcn_mfma_f32_16x16x32_bf16(afr[s], Bs[(1*7+s)*64 + L], acc1, 0,0,0);
          acc2 = __builtin_amdgcn_mfma_f32_16x16x32_bf16(afr[s], Bs[(2*7+s)*64 + L], acc2, 0,0,0);
          acc3 = __builtin_amdgcn_mfma_f32_16x16x32_bf16(afr[s], Bs[(3*7+s)*64 + L], acc3, 0,0,0);
        }

        // C/D: col = lane&15, row = (lane>>4)*4 + q. XSTR-padded rows.
        __bf16* dst = (__bf16*)&xs[pc & 1][(t8 * 16) * XSTR];
#pragma unroll
        for (int q = 0; q < 4; ++q) {
          __bf16* rowp = dst + (kg * 4 + q) * XSTR;
          rowp[ 0 + cb] = (bf16_t)((acc0[q] + bv[0]) * cs);
          rowp[16 + cb] = (bf16_t)((acc1[q] + bv[1]) * cs);
          rowp[32 + cb] = (bf16_t)((acc2[q] + bv[2]) * cs);
          rowp[48 + cb] = (bf16_t)((acc3[q] + bv[3]) * cs);
        }
      }
    };

    __syncthreads();                     // #1: Bs complete
    produce(0);
    for (int ch = 0; ch < NCH; ++ch) {
      __syncthreads();                   // #2..#9: chunk ch ready
      if (ch + 1 < NCH) produce(ch + 1);
    }
    __syncthreads();                     // #10: matches scanner's final
  } else {
    // ================= scanner wave (wave 0) — R11 body =================
    __builtin_amdgcn_s_setprio(1);
    const int g = lane & 3;
    const int j = lane >> 2;
    const int r = (g << 4) | j;

    const float sfac = (g == 2) ? (-2.f * LOG2E) : (-LOG2E);
    const float pfac = (g == 0) ? (2.f * LOG2E) : ((g == 2) ? 2.f : 1.f);
    const float qfac = (g == 2) ? -1.f : 0.f;

    half2_t wpk[8];
#pragma unroll
    for (int q = 0; q < 4; ++q) {
      float4 w = *reinterpret_cast<const float4*>(Whh + r * 16 + q * 4);
      wpk[q * 2 + 0] = __builtin_amdgcn_cvt_pkrtz(w.x * sfac, w.y * sfac);
      wpk[q * 2 + 1] = __builtin_amdgcn_cvt_pkrtz(w.z * sfac, w.w * sfac);
    }

    float c = c0[b * 16 + j] * (2.f * LOG2E);     // cell state in exp2 domain
    float hmine = h0[b * 16 + j];                 // quad-uniform
    int hp0, hp1, hp2, hp3, hp4, hp5, hp6, hp7;
    PACKH(hmine, hp0, hp1, hp2, hp3, hp4, hp5, hp6, hp7);

    __syncthreads();                              // #1
    __syncthreads();                              // #2: chunk 0 ready

    float buf[8];
#pragma unroll
    for (int u = 0; u < 8; ++u)
      buf[u] = bf2f(xs[0][u * XSTR + lane]);      // sfac pre-folded by producer

    for (int ch = 0; ch < NCH; ++ch) {
      const unsigned short* xcur = xs[ch & 1];

      for (int ts = 0; ts < CHUNK; ts += 8) {
        float hsv[8];
#pragma unroll
        for (int u = 0; u < 8; ++u) {
          const float gin = buf[u];
          int tn = ts + 8 + u;
          tn = (tn < CHUNK) ? tn : (CHUNK - 1);   // clamped dummy reload at tail
          buf[u] = bf2f(xcur[tn * XSTR + lane]);

          // pre = sfac*(Wx+b + Whh h): 4 chains of 2 dot2 + add tree
          float e0 = FDOT2(wpk[0], i2h2(hp0), gin);
          e0 = FDOT2(wpk[1], i2h2(hp1), e0);
          float e1 = FDOT2(wpk[2], i2h2(hp2), 0.f);
          e1 = FDOT2(wpk[3], i2h2(hp3), e1);
          float e2 = FDOT2(wpk[4], i2h2(hp4), 0.f);
          e2 = FDOT2(wpk[5], i2h2(hp5), e2);
          float e3 = FDOT2(wpk[6], i2h2(hp6), 0.f);
          e3 = FDOT2(wpk[7], i2h2(hp7), e3);
          float pre = (e0 + e1) + (e2 + e3);

          float e = fexp2(pre);
          float z = frcp(1.f + e);
          float y = fmaf(pfac, z, qfac);  // g0: 2log2e*i, g1: f, g2: tanh g, g3: o

          // c' = f*c' + (2log2e*i)*g via quad DPP combine
          float t1 = DPPF(y, 0x4E) * y;           // lane0: g*(2log2e*i)
          float ig = DPPF(t1, 0x00);              // broadcast lane0 to quad
          c = fmaf(DPPF(y, 0x55), c, ig);         // f from lane1

          float e2x = fexp2(c);                   // e^{2*c_true}
          float z2 = frcp(1.f + e2x);
          float th = fmaf(-2.f, z2, 1.f);         // tanh(c_true)
          float h = DPPF(y, 0xFF) * th;           // o from lane3; quad-uniform

          PACKH(h, hp0, hp1, hp2, hp3, hp4, hp5, hp6, hp7);
          hsv[u] = h;
        }
        if (g == 0) {                             // one 16B LDS write / 8 steps
          uint4 pk;
          pk.x = pkbf(hsv[0], hsv[1]);
          pk.y = pkbf(hsv[2], hsv[3]);
          pk.z = pkbf(hsv[4], hsv[5]);
          pk.w = pkbf(hsv[6], hsv[7]);
          *reinterpret_cast<uint4*>(&hstL[j * HSTR + ch * CHUNK + ts]) = pk;
        }
      }

      __syncthreads();                            // #(3+ch): next chunk ready
      if (ch + 1 < NCH) {
        const unsigned short* xn = xs[(ch + 1) & 1];
#pragma unroll
        for (int u = 0; u < 8; ++u) buf[u] = bf2f(xn[u * XSTR + lane]);
      }
    }
  }

  // ================= head phase (all 4 waves; hstL drained at barrier #10) ===
  float acc = 0.f;
#pragma unroll
  for (int it = 0; it < 4; ++it) {
    const int t = it * 256 + tid;
    float h[16];
#pragma unroll
    for (int jj = 0; jj < 16; ++jj)
      h[jj] = bf2f(hstL[jj * HSTR + t]);
    float s = b2s;
#pragma unroll
    for (int jj = 0; jj < 16; ++jj) {
      float p = wsb1[jj];
#pragma unroll
      for (int k = 0; k < 16; ++k) p = fmaf(ws1[jj * 16 + k], h[k], p);
      p = fmaxf(p, 0.f);
      s = fmaf(wsw2[jj], p, s);
    }
    acc += frcp(1.f + fexp2(-LOG2E * s));
  }

  red[tid] = acc;
  __syncthreads();
  if (tid < 128) red[tid] += red[tid + 128];
  __syncthreads();
  if (tid < 64) {
    float v = red[tid] + red[tid + 64];
    v += __shfl_xor(v, 32, 64);
    v += __shfl_xor(v, 16, 64);
    v += __shfl_xor(v, 8, 64);
    v += __shfl_xor(v, 4, 64);
    v += __shfl_xor(v, 2, 64);
    v += __shfl_xor(v, 1, 64);
    if (tid == 0) out[b] = v * (1.f / T_LEN);
  }
}

// ---------------- launcher ----------------
extern "C" void kernel_launch(void* const* d_in, const int* in_sizes, int n_in,
                              void* d_out, int out_size, void* d_ws, size_t ws_size,
                              hipStream_t stream) {
  const float* x   = (const float*)d_in[0];
  const float* h0  = (const float*)d_in[1];
  const float* c0  = (const float*)d_in[2];
  const float* Wih = (const float*)d_in[3];
  const float* Whh = (const float*)d_in[4];
  const float* bih = (const float*)d_in[5];
  const float* bhh = (const float*)d_in[6];
  const float* W1  = (const float*)d_in[7];
  const float* b1  = (const float*)d_in[8];
  const float* W2  = (const float*)d_in[9];
  const float* b2  = (const float*)d_in[10];

  hipLaunchKernelGGL(mega, dim3(NB), dim3(256), 0, stream,
                     x, Wih, bih, bhh, h0, c0, Whh, W1, b1, W2, b2,
                     (float*)d_out);
}